// Round 9
// baseline (637.062 us; speedup 1.0000x reference)
//
#include <hip/hip_runtime.h>
#include <hip/hip_cooperative_groups.h>

namespace cg = cooperative_groups;

#define N_NODES 50000
#define N_EDGES 800000
#define NB 49                 // 1024-element scan chunks covering 50K
#define W_ITEMS 49152
#define X_ITEMS (N_NODES * 16)
#define PREP_TOTAL (W_ITEMS + X_ITEMS + N_NODES)

typedef __attribute__((ext_vector_type(8))) short short8;
typedef __attribute__((ext_vector_type(4))) float floatx4;

// float -> bf16 bits, round-to-nearest-even
static __device__ __forceinline__ unsigned short f2b(float f) {
    unsigned int u = __float_as_uint(f);
    unsigned int r = u + 0x7fffu + ((u >> 16) & 1u);
    return (unsigned short)(r >> 16);
}
static __device__ __forceinline__ unsigned int pk(float a, float b) {
    return (unsigned)f2b(a) | ((unsigned)f2b(b) << 16);
}
static __device__ __forceinline__ float blo(unsigned int u) {
    return __uint_as_float(u << 16);
}
static __device__ __forceinline__ float bhi(unsigned int u) {
    return __uint_as_float(u & 0xffff0000u);
}

// ---------------------------------------------------------------------------
// Cooperative CSR+prep mega-kernel: ONE dispatch replaces
// prep / hist_rank / scanA / scanC / fill. grid.sync() between phases.
// 1024 blocks x 256 threads: low VGPR, 1KB LDS -> fully co-resident.
// ---------------------------------------------------------------------------
__global__ __launch_bounds__(256) void csr_mega_kernel(
    const float* __restrict__ x, const int* __restrict__ src,
    const int* __restrict__ dst, const float* __restrict__ W1a,
    const float* __restrict__ W1b, const float* __restrict__ W2a,
    const float* __restrict__ W2b, unsigned short* __restrict__ W1aT,
    unsigned short* __restrict__ W1bT, unsigned short* __restrict__ W2aT,
    unsigned short* __restrict__ W2bT, unsigned short* __restrict__ xb,
    int* __restrict__ deg, int* __restrict__ off, int* __restrict__ bsum,
    int* __restrict__ rank, unsigned short* __restrict__ nbr) {
    cg::grid_group grid = cg::this_grid();
    const int tid = threadIdx.x;
    const int bid = blockIdx.x;
    const int nth = gridDim.x * 256;
    const int gtid = bid * 256 + tid;
    __shared__ int sscan[256];
    __shared__ int sbpref;

    // ---- Phase 0: weight transpose->bf16 [N][K], x->bf16, deg=0 ----
    for (int i = gtid; i < PREP_TOTAL; i += nth) {
        if (i < 8192) {                        // W1a [64][128] -> [128][64]
            int n = i >> 6, k = i & 63;
            W1aT[i] = f2b(W1a[k * 128 + n]);
        } else if (i < 24576) {                // W1b -> [128][128]
            int j = i - 8192, n = j >> 7, k = j & 127;
            W1bT[j] = f2b(W1b[k * 128 + n]);
        } else if (i < 40960) {                // W2a -> [128][128]
            int j = i - 24576, n = j >> 7, k = j & 127;
            W2aT[j] = f2b(W2a[k * 128 + n]);
        } else if (i < 49152) {                // W2b [128][64] -> [64][128]
            int j = i - 40960, n = j >> 7, k = j & 127;
            W2bT[j] = f2b(W2b[k * 64 + n]);
        } else if (i < 49152 + X_ITEMS) {      // x convert, float4 -> 4x bf16
            int j = i - 49152;
            float4 v = ((const float4*)x)[j];
            uint2 o;
            o.x = pk(v.x, v.y);
            o.y = pk(v.z, v.w);
            ((uint2*)xb)[j] = o;
        } else {                               // zero deg
            deg[i - (49152 + X_ITEMS)] = 0;
        }
    }
    grid.sync();

    // ---- Phase 1: histogram + per-edge rank (atomic return value) ----
    for (int e = gtid; e < N_EDGES; e += nth)
        rank[e] = atomicAdd(&deg[dst[e]], 1);
    grid.sync();

    // ---- Phase 2: per-chunk sums (blocks 0..NB-1, 4 elems/thread) ----
    if (bid < NB) {
        const int base = bid * 1024 + tid * 4;
        int s = 0;
#pragma unroll
        for (int k = 0; k < 4; ++k) {
            int i = base + k;
            if (i < N_NODES) s += deg[i];
        }
        sscan[tid] = s;
        __syncthreads();
        for (int d = 128; d > 0; d >>= 1) {
            if (tid < d) sscan[tid] += sscan[tid + d];
            __syncthreads();
        }
        if (tid == 0) bsum[bid] = sscan[0];
    }
    grid.sync();

    // ---- Phase 3: exclusive scan -> off (blocks 0..NB-1) ----
    if (bid < NB) {
        if (tid == 0) {
            int p = 0;
            for (int j = 0; j < bid; ++j) p += bsum[j];
            sbpref = p;
        }
        const int base = bid * 1024 + tid * 4;
        int v[4];
        int ls = 0;
#pragma unroll
        for (int k = 0; k < 4; ++k) {
            int i = base + k;
            v[k] = (i < N_NODES) ? deg[i] : 0;
            ls += v[k];
        }
        sscan[tid] = ls;
        __syncthreads();
        for (int d = 1; d < 256; d <<= 1) {
            int t = (tid >= d) ? sscan[tid - d] : 0;
            __syncthreads();
            sscan[tid] += t;
            __syncthreads();
        }
        int run = sbpref + sscan[tid] - ls;
#pragma unroll
        for (int k = 0; k < 4; ++k) {
            int i = base + k;
            if (i < N_NODES) {
                off[i] = run;
                run += v[k];
                if (i == N_NODES - 1) off[N_NODES] = run;
            }
        }
    }
    grid.sync();

    // ---- Phase 4: atomic-free fill (no latency chain) ----
    for (int e = gtid; e < N_EDGES; e += nth)
        nbr[off[dst[e]] + rank[e]] = (unsigned short)src[e];
}

// ---------------------------------------------------------------------------
// Gather (d=64 bf16): t1 = bf16(x_i + sum_nbr x_j). 16 lanes/node, 8B/lane,
// neighbor loop unrolled x8 -> 8 independent row loads in flight per thread
// (latency-bound workload; occupancy high, no LDS).
// ---------------------------------------------------------------------------
__global__ __launch_bounds__(256) void gather1_kernel(
    const unsigned short* __restrict__ xb, const int* __restrict__ off,
    const unsigned short* __restrict__ nbr, unsigned short* __restrict__ t1,
    int n_nodes) {
    const int tid = threadIdx.x;
    const int node = blockIdx.x * 16 + (tid >> 4);
    const int c = tid & 15;
    if (node >= n_nodes) return;
    const uint2* xr = (const uint2*)xb;
    const uint2 a = xr[(size_t)node * 16 + c];
    float f0 = blo(a.x), f1 = bhi(a.x), f2 = blo(a.y), f3 = bhi(a.y);
    const int lo = off[node], hi = off[node + 1];
    int j = lo;
    for (; j + 8 <= hi; j += 8) {
        const int s0 = nbr[j], s1 = nbr[j + 1], s2 = nbr[j + 2],
                  s3 = nbr[j + 3], s4 = nbr[j + 4], s5 = nbr[j + 5],
                  s6 = nbr[j + 6], s7 = nbr[j + 7];
        const uint2 v0 = xr[(size_t)s0 * 16 + c];
        const uint2 v1 = xr[(size_t)s1 * 16 + c];
        const uint2 v2 = xr[(size_t)s2 * 16 + c];
        const uint2 v3 = xr[(size_t)s3 * 16 + c];
        const uint2 v4 = xr[(size_t)s4 * 16 + c];
        const uint2 v5 = xr[(size_t)s5 * 16 + c];
        const uint2 v6 = xr[(size_t)s6 * 16 + c];
        const uint2 v7 = xr[(size_t)s7 * 16 + c];
        f0 += ((blo(v0.x) + blo(v1.x)) + (blo(v2.x) + blo(v3.x))) +
              ((blo(v4.x) + blo(v5.x)) + (blo(v6.x) + blo(v7.x)));
        f1 += ((bhi(v0.x) + bhi(v1.x)) + (bhi(v2.x) + bhi(v3.x))) +
              ((bhi(v4.x) + bhi(v5.x)) + (bhi(v6.x) + bhi(v7.x)));
        f2 += ((blo(v0.y) + blo(v1.y)) + (blo(v2.y) + blo(v3.y))) +
              ((blo(v4.y) + blo(v5.y)) + (blo(v6.y) + blo(v7.y)));
        f3 += ((bhi(v0.y) + bhi(v1.y)) + (bhi(v2.y) + bhi(v3.y))) +
              ((bhi(v4.y) + bhi(v5.y)) + (bhi(v6.y) + bhi(v7.y)));
    }
    for (; j < hi; ++j) {
        const uint2 v = xr[(size_t)nbr[j] * 16 + c];
        f0 += blo(v.x); f1 += bhi(v.x);
        f2 += blo(v.y); f3 += bhi(v.y);
    }
    uint2 o;
    o.x = pk(f0, f1);
    o.y = pk(f2, f3);
    ((uint2*)t1)[(size_t)node * 16 + c] = o;
}

// Gather (d=128 bf16): 16 lanes/node, 16B/lane, unrolled x8.
__global__ __launch_bounds__(256) void gather2_kernel(
    const unsigned short* __restrict__ h, const int* __restrict__ off,
    const unsigned short* __restrict__ nbr, unsigned short* __restrict__ t2,
    int n_nodes) {
    const int tid = threadIdx.x;
    const int node = blockIdx.x * 16 + (tid >> 4);
    const int c = tid & 15;
    if (node >= n_nodes) return;
    const uint4* hr = (const uint4*)h;
    const uint4 a = hr[(size_t)node * 16 + c];
    float f0 = blo(a.x), f1 = bhi(a.x), f2 = blo(a.y), f3 = bhi(a.y);
    float f4 = blo(a.z), f5 = bhi(a.z), f6 = blo(a.w), f7 = bhi(a.w);
    const int lo = off[node], hi = off[node + 1];
    int j = lo;
    for (; j + 8 <= hi; j += 8) {
        const int s0 = nbr[j], s1 = nbr[j + 1], s2 = nbr[j + 2],
                  s3 = nbr[j + 3], s4 = nbr[j + 4], s5 = nbr[j + 5],
                  s6 = nbr[j + 6], s7 = nbr[j + 7];
        const uint4 v0 = hr[(size_t)s0 * 16 + c];
        const uint4 v1 = hr[(size_t)s1 * 16 + c];
        const uint4 v2 = hr[(size_t)s2 * 16 + c];
        const uint4 v3 = hr[(size_t)s3 * 16 + c];
        const uint4 v4 = hr[(size_t)s4 * 16 + c];
        const uint4 v5 = hr[(size_t)s5 * 16 + c];
        const uint4 v6 = hr[(size_t)s6 * 16 + c];
        const uint4 v7 = hr[(size_t)s7 * 16 + c];
        f0 += ((blo(v0.x) + blo(v1.x)) + (blo(v2.x) + blo(v3.x))) +
              ((blo(v4.x) + blo(v5.x)) + (blo(v6.x) + blo(v7.x)));
        f1 += ((bhi(v0.x) + bhi(v1.x)) + (bhi(v2.x) + bhi(v3.x))) +
              ((bhi(v4.x) + bhi(v5.x)) + (bhi(v6.x) + bhi(v7.x)));
        f2 += ((blo(v0.y) + blo(v1.y)) + (blo(v2.y) + blo(v3.y))) +
              ((blo(v4.y) + blo(v5.y)) + (blo(v6.y) + blo(v7.y)));
        f3 += ((bhi(v0.y) + bhi(v1.y)) + (bhi(v2.y) + bhi(v3.y))) +
              ((bhi(v4.y) + bhi(v5.y)) + (bhi(v6.y) + bhi(v7.y)));
        f4 += ((blo(v0.z) + blo(v1.z)) + (blo(v2.z) + blo(v3.z))) +
              ((blo(v4.z) + blo(v5.z)) + (blo(v6.z) + blo(v7.z)));
        f5 += ((bhi(v0.z) + bhi(v1.z)) + (bhi(v2.z) + bhi(v3.z))) +
              ((bhi(v4.z) + bhi(v5.z)) + (bhi(v6.z) + bhi(v7.z)));
        f6 += ((blo(v0.w) + blo(v1.w)) + (blo(v2.w) + blo(v3.w))) +
              ((blo(v4.w) + blo(v5.w)) + (blo(v6.w) + blo(v7.w)));
        f7 += ((bhi(v0.w) + bhi(v1.w)) + (bhi(v2.w) + bhi(v3.w))) +
              ((bhi(v4.w) + bhi(v5.w)) + (bhi(v6.w) + bhi(v7.w)));
    }
    for (; j < hi; ++j) {
        const uint4 v = hr[(size_t)nbr[j] * 16 + c];
        f0 += blo(v.x); f1 += bhi(v.x); f2 += blo(v.y); f3 += bhi(v.y);
        f4 += blo(v.z); f5 += bhi(v.z); f6 += blo(v.w); f7 += bhi(v.w);
    }
    uint4 o;
    o.x = pk(f0, f1); o.y = pk(f2, f3);
    o.z = pk(f4, f5); o.w = pk(f6, f7);
    ((uint4*)t2)[(size_t)node * 16 + c] = o;
}

// ---------------------------------------------------------------------------
// 2-layer MLP via MFMA 16x16x32 bf16, fp32 accumulate (round-4 verified).
//   out = relu( relu(T @ Wa + ba) @ Wb + bb )
// Block = 256 thr (4 waves), 64 rows; wave w owns rows [w*16, w*16+16).
// C/D layout: col=lane&15, row=quad*4+reg. No barrier between phases (each
// wave reads back only its own hidden strip).
// ---------------------------------------------------------------------------
template <int DIN, int DH, int DOUT, bool OUT_BF16>
__global__ __launch_bounds__(256) void mlp_mfma_kernel(
    const unsigned short* __restrict__ t, const unsigned short* __restrict__ WaT,
    const float* __restrict__ ba, const unsigned short* __restrict__ WbT,
    const float* __restrict__ bb, void* __restrict__ outp, int n_rows) {
    constexpr int SA = DIN + 16;
    constexpr int SH = DH + 16;
    __shared__ unsigned short tA[64 * SA];
    __shared__ unsigned short hidA[64 * SH];

    const int tid = threadIdx.x;
    const int row0 = blockIdx.x * 64;

    constexpr int CHUNKS = 64 * DIN / 8;
    const uint4* tg = (const uint4*)t;
    for (int i = tid; i < CHUNKS; i += 256) {
        const int row = i / (DIN / 8);
        const int cb = i % (DIN / 8);
        uint4 v = {0u, 0u, 0u, 0u};
        const int gr = row0 + row;
        if (gr < n_rows) v = tg[(size_t)gr * (DIN / 8) + cb];
        *(uint4*)&tA[row * SA + cb * 8] = v;
    }
    __syncthreads();

    const int lane = tid & 63;
    const int wv = tid >> 6;
    const int quad = lane >> 4;
    const int l16 = lane & 15;
    const int m0 = wv * 16;

    short8 a1[DIN / 32];
#pragma unroll
    for (int kk = 0; kk < DIN / 32; ++kk)
        a1[kk] = *(const short8*)&tA[(m0 + l16) * SA + kk * 32 + quad * 8];
#pragma unroll
    for (int nt = 0; nt < DH / 16; ++nt) {
        floatx4 acc = {0.f, 0.f, 0.f, 0.f};
#pragma unroll
        for (int kk = 0; kk < DIN / 32; ++kk) {
            short8 b =
                *(const short8*)&WaT[(nt * 16 + l16) * DIN + kk * 32 + quad * 8];
            acc = __builtin_amdgcn_mfma_f32_16x16x32_bf16(a1[kk], b, acc, 0, 0, 0);
        }
        const float bias = ba[nt * 16 + l16];
#pragma unroll
        for (int r = 0; r < 4; ++r) {
            const float v = fmaxf(acc[r] + bias, 0.f);
            hidA[(m0 + quad * 4 + r) * SH + nt * 16 + l16] = f2b(v);
        }
    }

    short8 a2[DH / 32];
#pragma unroll
    for (int kk = 0; kk < DH / 32; ++kk)
        a2[kk] = *(const short8*)&hidA[(m0 + l16) * SH + kk * 32 + quad * 8];
#pragma unroll
    for (int nt = 0; nt < DOUT / 16; ++nt) {
        floatx4 acc = {0.f, 0.f, 0.f, 0.f};
#pragma unroll
        for (int kk = 0; kk < DH / 32; ++kk) {
            short8 b =
                *(const short8*)&WbT[(nt * 16 + l16) * DH + kk * 32 + quad * 8];
            acc = __builtin_amdgcn_mfma_f32_16x16x32_bf16(a2[kk], b, acc, 0, 0, 0);
        }
        const float bias = bb[nt * 16 + l16];
#pragma unroll
        for (int r = 0; r < 4; ++r) {
            const float v = fmaxf(acc[r] + bias, 0.f);
            const int grow = row0 + m0 + quad * 4 + r;
            if (grow < n_rows) {
                if (OUT_BF16)
                    ((unsigned short*)outp)[(size_t)grow * DOUT + nt * 16 + l16] =
                        f2b(v);
                else
                    ((float*)outp)[(size_t)grow * DOUT + nt * 16 + l16] = v;
            }
        }
    }
}

extern "C" void kernel_launch(void* const* d_in, const int* in_sizes, int n_in,
                              void* d_out, int out_size, void* d_ws,
                              size_t ws_size, hipStream_t stream) {
    const float* x   = (const float*)d_in[0];
    const int*   ei  = (const int*)d_in[1];  // [2, N_EDGES] int32
    const float* W1a = (const float*)d_in[2];
    const float* b1a = (const float*)d_in[3];
    const float* W1b = (const float*)d_in[4];
    const float* b1b = (const float*)d_in[5];
    const float* W2a = (const float*)d_in[6];
    const float* b2a = (const float*)d_in[7];
    const float* W2b = (const float*)d_in[8];
    const float* b2b = (const float*)d_in[9];
    float* out = (float*)d_out;

    const int* src = ei;
    const int* dst = ei + N_EDGES;

    // Workspace: bf16 xb[N,64] t1[N,64] h[N,128] t2[N,128] | bf16 weightsT |
    //            int deg/off/bsum/rank | ushort nbr[E]
    unsigned short* xb = (unsigned short*)d_ws;
    unsigned short* t1 = xb + (size_t)N_NODES * 64;
    unsigned short* h  = t1 + (size_t)N_NODES * 64;
    unsigned short* t2 = h + (size_t)N_NODES * 128;
    unsigned short* W1aT = t2 + (size_t)N_NODES * 128;
    unsigned short* W1bT = W1aT + 8192;
    unsigned short* W2aT = W1bT + 16384;
    unsigned short* W2bT = W2aT + 16384;
    int* deg  = (int*)(W2bT + 8192);
    int* off  = deg + N_NODES;
    int* bsum = off + N_NODES + 1;
    int* rank = bsum + 64;
    unsigned short* nbr = (unsigned short*)(rank + N_EDGES);

    // ---- CSR build + prep: ONE cooperative dispatch ----
    void* args[] = {(void*)&x,    (void*)&src,  (void*)&dst,  (void*)&W1a,
                    (void*)&W1b,  (void*)&W2a,  (void*)&W2b,  (void*)&W1aT,
                    (void*)&W1bT, (void*)&W2aT, (void*)&W2bT, (void*)&xb,
                    (void*)&deg,  (void*)&off,  (void*)&bsum, (void*)&rank,
                    (void*)&nbr};
    hipLaunchCooperativeKernel((const void*)csr_mega_kernel, dim3(1024),
                               dim3(256), args, 0, stream);

    // ---- Layer 1 ----
    gather1_kernel<<<(N_NODES + 15) / 16, 256, 0, stream>>>(xb, off, nbr, t1,
                                                            N_NODES);
    mlp_mfma_kernel<64, 128, 128, true>
        <<<(N_NODES + 63) / 64, 256, 0, stream>>>(t1, W1aT, b1a, W1bT, b1b, h,
                                                  N_NODES);

    // ---- Layer 2 ----
    gather2_kernel<<<(N_NODES + 15) / 16, 256, 0, stream>>>(h, off, nbr, t2,
                                                            N_NODES);
    mlp_mfma_kernel<128, 128, 64, false>
        <<<(N_NODES + 63) / 64, 256, 0, stream>>>(t2, W2aT, b2a, W2bT, b2b, out,
                                                  N_NODES);
}

// Round 10
// 242.586 us; speedup vs baseline: 2.6261x; 2.6261x over previous
//
#include <hip/hip_runtime.h>

#define N_NODES 50000
#define N_EDGES 800000

typedef __attribute__((ext_vector_type(8))) short short8;
typedef __attribute__((ext_vector_type(4))) float floatx4;

// float -> bf16 bits, round-to-nearest-even
static __device__ __forceinline__ unsigned short f2b(float f) {
    unsigned int u = __float_as_uint(f);
    unsigned int r = u + 0x7fffu + ((u >> 16) & 1u);
    return (unsigned short)(r >> 16);
}
static __device__ __forceinline__ unsigned int pk(float a, float b) {
    return (unsigned)f2b(a) | ((unsigned)f2b(b) << 16);
}
static __device__ __forceinline__ float blo(unsigned int u) {
    return __uint_as_float(u << 16);
}
static __device__ __forceinline__ float bhi(unsigned int u) {
    return __uint_as_float(u & 0xffff0000u);
}

// ---------------------------------------------------------------------------
// CSR build. hist_rank: deg histogram AND per-edge rank in one pass — the
// atomicAdd return value is the edge's slot within its dst segment. fill is
// then atomic-free (no latency chain): pure coalesced loads + scattered store.
// NOTE (R9): cooperative grid.sync() mega-kernel costs ~100us/barrier at this
// grid size — separate dispatches are an order of magnitude cheaper.
// ---------------------------------------------------------------------------
__global__ void hist_rank_kernel(const int* __restrict__ dst,
                                 int* __restrict__ deg, int* __restrict__ rank,
                                 int n) {
    int i = blockIdx.x * blockDim.x + threadIdx.x;
    if (i < n) rank[i] = atomicAdd(&deg[dst[i]], 1);
}

__global__ __launch_bounds__(1024) void scanA_kernel(
    const int* __restrict__ deg, int* __restrict__ bsum, int n) {
    __shared__ int s[1024];
    const int tid = threadIdx.x;
    int i = blockIdx.x * 1024 + tid;
    s[tid] = (i < n) ? deg[i] : 0;
    __syncthreads();
    for (int d = 512; d > 0; d >>= 1) {
        if (tid < d) s[tid] += s[tid + d];
        __syncthreads();
    }
    if (tid == 0) bsum[blockIdx.x] = s[0];
}

// In-block exclusive scan + serial 49-entry block prefix (cheaper than a
// separate scanB dispatch).
__global__ __launch_bounds__(1024) void scanC_kernel(
    const int* __restrict__ deg, const int* __restrict__ bsum,
    int* __restrict__ off, int n) {
    __shared__ int s[1024];
    __shared__ int bpref;
    const int tid = threadIdx.x;
    if (tid == 0) {
        int p = 0;
        for (int j = 0; j < blockIdx.x; ++j) p += bsum[j];
        bpref = p;
    }
    const int i = blockIdx.x * 1024 + tid;
    const int v = (i < n) ? deg[i] : 0;
    s[tid] = v;
    __syncthreads();
    for (int d = 1; d < 1024; d <<= 1) {
        int t = (tid >= d) ? s[tid - d] : 0;
        __syncthreads();
        s[tid] += t;
        __syncthreads();
    }
    const int excl = s[tid] - v + bpref;
    if (i < n) {
        off[i] = excl;
        if (i == n - 1) off[n] = excl + v;
    }
}

// Atomic-free fill: pos precomputed from off + rank. Fire-and-forget stores.
__global__ void fill_kernel(const int* __restrict__ src,
                            const int* __restrict__ dst,
                            const int* __restrict__ rank,
                            const int* __restrict__ off,
                            unsigned short* __restrict__ nbr, int n) {
    int i = blockIdx.x * blockDim.x + threadIdx.x;
    if (i < n) nbr[off[dst[i]] + rank[i]] = (unsigned short)src[i];
}

// ---------------------------------------------------------------------------
// Fused prep: weight transpose->bf16 [N][K] + x fp32->bf16 + deg zeroing.
// ---------------------------------------------------------------------------
__global__ __launch_bounds__(256) void prep_kernel(
    const float* __restrict__ W1a, const float* __restrict__ W1b,
    const float* __restrict__ W2a, const float* __restrict__ W2b,
    const float* __restrict__ x, unsigned short* __restrict__ W1aT,
    unsigned short* __restrict__ W1bT, unsigned short* __restrict__ W2aT,
    unsigned short* __restrict__ W2bT, unsigned short* __restrict__ xb,
    int* __restrict__ deg) {
    int i = blockIdx.x * 256 + threadIdx.x;
    if (i < 8192) {                       // W1a [64][128] -> [128][64]
        int n = i >> 6, k = i & 63;
        W1aT[i] = f2b(W1a[k * 128 + n]);
    } else if (i < 24576) {               // W1b [128][128] -> [128][128]
        int j = i - 8192, n = j >> 7, k = j & 127;
        W1bT[j] = f2b(W1b[k * 128 + n]);
    } else if (i < 40960) {               // W2a [128][128] -> [128][128]
        int j = i - 24576, n = j >> 7, k = j & 127;
        W2aT[j] = f2b(W2a[k * 128 + n]);
    } else if (i < 49152) {               // W2b [128][64] -> [64][128]
        int j = i - 40960, n = j >> 7, k = j & 127;
        W2bT[j] = f2b(W2b[k * 64 + n]);
    } else if (i < 49152 + N_NODES * 16) {  // x convert: float4 -> 4x bf16
        int j = i - 49152;
        float4 v = ((const float4*)x)[j];
        uint2 o;
        o.x = pk(v.x, v.y);
        o.y = pk(v.z, v.w);
        ((uint2*)xb)[j] = o;
    } else {                              // zero deg
        int j = i - (49152 + N_NODES * 16);
        if (j < N_NODES) deg[j] = 0;
    }
}

// ---------------------------------------------------------------------------
// Gather (d=64 bf16): t1 = bf16(x_i + sum_nbr x_j). 16 lanes/node, 8B/lane,
// neighbor loop unrolled x8 -> 8 independent row loads in flight per thread
// (latency-bound workload; no LDS, full occupancy).
// ---------------------------------------------------------------------------
__global__ __launch_bounds__(256) void gather1_kernel(
    const unsigned short* __restrict__ xb, const int* __restrict__ off,
    const unsigned short* __restrict__ nbr, unsigned short* __restrict__ t1,
    int n_nodes) {
    const int tid = threadIdx.x;
    const int node = blockIdx.x * 16 + (tid >> 4);
    const int c = tid & 15;
    if (node >= n_nodes) return;
    const uint2* xr = (const uint2*)xb;
    const uint2 a = xr[(size_t)node * 16 + c];
    float f0 = blo(a.x), f1 = bhi(a.x), f2 = blo(a.y), f3 = bhi(a.y);
    const int lo = off[node], hi = off[node + 1];
    int j = lo;
    for (; j + 8 <= hi; j += 8) {
        const int s0 = nbr[j], s1 = nbr[j + 1], s2 = nbr[j + 2],
                  s3 = nbr[j + 3], s4 = nbr[j + 4], s5 = nbr[j + 5],
                  s6 = nbr[j + 6], s7 = nbr[j + 7];
        const uint2 v0 = xr[(size_t)s0 * 16 + c];
        const uint2 v1 = xr[(size_t)s1 * 16 + c];
        const uint2 v2 = xr[(size_t)s2 * 16 + c];
        const uint2 v3 = xr[(size_t)s3 * 16 + c];
        const uint2 v4 = xr[(size_t)s4 * 16 + c];
        const uint2 v5 = xr[(size_t)s5 * 16 + c];
        const uint2 v6 = xr[(size_t)s6 * 16 + c];
        const uint2 v7 = xr[(size_t)s7 * 16 + c];
        f0 += ((blo(v0.x) + blo(v1.x)) + (blo(v2.x) + blo(v3.x))) +
              ((blo(v4.x) + blo(v5.x)) + (blo(v6.x) + blo(v7.x)));
        f1 += ((bhi(v0.x) + bhi(v1.x)) + (bhi(v2.x) + bhi(v3.x))) +
              ((bhi(v4.x) + bhi(v5.x)) + (bhi(v6.x) + bhi(v7.x)));
        f2 += ((blo(v0.y) + blo(v1.y)) + (blo(v2.y) + blo(v3.y))) +
              ((blo(v4.y) + blo(v5.y)) + (blo(v6.y) + blo(v7.y)));
        f3 += ((bhi(v0.y) + bhi(v1.y)) + (bhi(v2.y) + bhi(v3.y))) +
              ((bhi(v4.y) + bhi(v5.y)) + (bhi(v6.y) + bhi(v7.y)));
    }
    for (; j < hi; ++j) {
        const uint2 v = xr[(size_t)nbr[j] * 16 + c];
        f0 += blo(v.x); f1 += bhi(v.x);
        f2 += blo(v.y); f3 += bhi(v.y);
    }
    uint2 o;
    o.x = pk(f0, f1);
    o.y = pk(f2, f3);
    ((uint2*)t1)[(size_t)node * 16 + c] = o;
}

// Gather (d=128 bf16): 16 lanes/node, 16B/lane, unrolled x8.
__global__ __launch_bounds__(256) void gather2_kernel(
    const unsigned short* __restrict__ h, const int* __restrict__ off,
    const unsigned short* __restrict__ nbr, unsigned short* __restrict__ t2,
    int n_nodes) {
    const int tid = threadIdx.x;
    const int node = blockIdx.x * 16 + (tid >> 4);
    const int c = tid & 15;
    if (node >= n_nodes) return;
    const uint4* hr = (const uint4*)h;
    const uint4 a = hr[(size_t)node * 16 + c];
    float f0 = blo(a.x), f1 = bhi(a.x), f2 = blo(a.y), f3 = bhi(a.y);
    float f4 = blo(a.z), f5 = bhi(a.z), f6 = blo(a.w), f7 = bhi(a.w);
    const int lo = off[node], hi = off[node + 1];
    int j = lo;
    for (; j + 8 <= hi; j += 8) {
        const int s0 = nbr[j], s1 = nbr[j + 1], s2 = nbr[j + 2],
                  s3 = nbr[j + 3], s4 = nbr[j + 4], s5 = nbr[j + 5],
                  s6 = nbr[j + 6], s7 = nbr[j + 7];
        const uint4 v0 = hr[(size_t)s0 * 16 + c];
        const uint4 v1 = hr[(size_t)s1 * 16 + c];
        const uint4 v2 = hr[(size_t)s2 * 16 + c];
        const uint4 v3 = hr[(size_t)s3 * 16 + c];
        const uint4 v4 = hr[(size_t)s4 * 16 + c];
        const uint4 v5 = hr[(size_t)s5 * 16 + c];
        const uint4 v6 = hr[(size_t)s6 * 16 + c];
        const uint4 v7 = hr[(size_t)s7 * 16 + c];
        f0 += ((blo(v0.x) + blo(v1.x)) + (blo(v2.x) + blo(v3.x))) +
              ((blo(v4.x) + blo(v5.x)) + (blo(v6.x) + blo(v7.x)));
        f1 += ((bhi(v0.x) + bhi(v1.x)) + (bhi(v2.x) + bhi(v3.x))) +
              ((bhi(v4.x) + bhi(v5.x)) + (bhi(v6.x) + bhi(v7.x)));
        f2 += ((blo(v0.y) + blo(v1.y)) + (blo(v2.y) + blo(v3.y))) +
              ((blo(v4.y) + blo(v5.y)) + (blo(v6.y) + blo(v7.y)));
        f3 += ((bhi(v0.y) + bhi(v1.y)) + (bhi(v2.y) + bhi(v3.y))) +
              ((bhi(v4.y) + bhi(v5.y)) + (bhi(v6.y) + bhi(v7.y)));
        f4 += ((blo(v0.z) + blo(v1.z)) + (blo(v2.z) + blo(v3.z))) +
              ((blo(v4.z) + blo(v5.z)) + (blo(v6.z) + blo(v7.z)));
        f5 += ((bhi(v0.z) + bhi(v1.z)) + (bhi(v2.z) + bhi(v3.z))) +
              ((bhi(v4.z) + bhi(v5.z)) + (bhi(v6.z) + bhi(v7.z)));
        f6 += ((blo(v0.w) + blo(v1.w)) + (blo(v2.w) + blo(v3.w))) +
              ((blo(v4.w) + blo(v5.w)) + (blo(v6.w) + blo(v7.w)));
        f7 += ((bhi(v0.w) + bhi(v1.w)) + (bhi(v2.w) + bhi(v3.w))) +
              ((bhi(v4.w) + bhi(v5.w)) + (bhi(v6.w) + bhi(v7.w)));
    }
    for (; j < hi; ++j) {
        const uint4 v = hr[(size_t)nbr[j] * 16 + c];
        f0 += blo(v.x); f1 += bhi(v.x); f2 += blo(v.y); f3 += bhi(v.y);
        f4 += blo(v.z); f5 += bhi(v.z); f6 += blo(v.w); f7 += bhi(v.w);
    }
    uint4 o;
    o.x = pk(f0, f1); o.y = pk(f2, f3);
    o.z = pk(f4, f5); o.w = pk(f6, f7);
    ((uint4*)t2)[(size_t)node * 16 + c] = o;
}

// ---------------------------------------------------------------------------
// 2-layer MLP via MFMA 16x16x32 bf16, fp32 accumulate (round-4 verified).
//   out = relu( relu(T @ Wa + ba) @ Wb + bb )
// Block = 256 thr (4 waves), 64 rows; wave w owns rows [w*16, w*16+16).
// C/D layout: col=lane&15, row=quad*4+reg. No barrier between phases (each
// wave reads back only its own hidden strip).
// ---------------------------------------------------------------------------
template <int DIN, int DH, int DOUT, bool OUT_BF16>
__global__ __launch_bounds__(256) void mlp_mfma_kernel(
    const unsigned short* __restrict__ t, const unsigned short* __restrict__ WaT,
    const float* __restrict__ ba, const unsigned short* __restrict__ WbT,
    const float* __restrict__ bb, void* __restrict__ outp, int n_rows) {
    constexpr int SA = DIN + 16;
    constexpr int SH = DH + 16;
    __shared__ unsigned short tA[64 * SA];
    __shared__ unsigned short hidA[64 * SH];

    const int tid = threadIdx.x;
    const int row0 = blockIdx.x * 64;

    constexpr int CHUNKS = 64 * DIN / 8;
    const uint4* tg = (const uint4*)t;
    for (int i = tid; i < CHUNKS; i += 256) {
        const int row = i / (DIN / 8);
        const int cb = i % (DIN / 8);
        uint4 v = {0u, 0u, 0u, 0u};
        const int gr = row0 + row;
        if (gr < n_rows) v = tg[(size_t)gr * (DIN / 8) + cb];
        *(uint4*)&tA[row * SA + cb * 8] = v;
    }
    __syncthreads();

    const int lane = tid & 63;
    const int wv = tid >> 6;
    const int quad = lane >> 4;
    const int l16 = lane & 15;
    const int m0 = wv * 16;

    short8 a1[DIN / 32];
#pragma unroll
    for (int kk = 0; kk < DIN / 32; ++kk)
        a1[kk] = *(const short8*)&tA[(m0 + l16) * SA + kk * 32 + quad * 8];
#pragma unroll
    for (int nt = 0; nt < DH / 16; ++nt) {
        floatx4 acc = {0.f, 0.f, 0.f, 0.f};
#pragma unroll
        for (int kk = 0; kk < DIN / 32; ++kk) {
            short8 b =
                *(const short8*)&WaT[(nt * 16 + l16) * DIN + kk * 32 + quad * 8];
            acc = __builtin_amdgcn_mfma_f32_16x16x32_bf16(a1[kk], b, acc, 0, 0, 0);
        }
        const float bias = ba[nt * 16 + l16];
#pragma unroll
        for (int r = 0; r < 4; ++r) {
            const float v = fmaxf(acc[r] + bias, 0.f);
            hidA[(m0 + quad * 4 + r) * SH + nt * 16 + l16] = f2b(v);
        }
    }

    short8 a2[DH / 32];
#pragma unroll
    for (int kk = 0; kk < DH / 32; ++kk)
        a2[kk] = *(const short8*)&hidA[(m0 + l16) * SH + kk * 32 + quad * 8];
#pragma unroll
    for (int nt = 0; nt < DOUT / 16; ++nt) {
        floatx4 acc = {0.f, 0.f, 0.f, 0.f};
#pragma unroll
        for (int kk = 0; kk < DH / 32; ++kk) {
            short8 b =
                *(const short8*)&WbT[(nt * 16 + l16) * DH + kk * 32 + quad * 8];
            acc = __builtin_amdgcn_mfma_f32_16x16x32_bf16(a2[kk], b, acc, 0, 0, 0);
        }
        const float bias = bb[nt * 16 + l16];
#pragma unroll
        for (int r = 0; r < 4; ++r) {
            const float v = fmaxf(acc[r] + bias, 0.f);
            const int grow = row0 + m0 + quad * 4 + r;
            if (grow < n_rows) {
                if (OUT_BF16)
                    ((unsigned short*)outp)[(size_t)grow * DOUT + nt * 16 + l16] =
                        f2b(v);
                else
                    ((float*)outp)[(size_t)grow * DOUT + nt * 16 + l16] = v;
            }
        }
    }
}

extern "C" void kernel_launch(void* const* d_in, const int* in_sizes, int n_in,
                              void* d_out, int out_size, void* d_ws,
                              size_t ws_size, hipStream_t stream) {
    const float* x   = (const float*)d_in[0];
    const int*   ei  = (const int*)d_in[1];  // [2, N_EDGES] int32
    const float* W1a = (const float*)d_in[2];
    const float* b1a = (const float*)d_in[3];
    const float* W1b = (const float*)d_in[4];
    const float* b1b = (const float*)d_in[5];
    const float* W2a = (const float*)d_in[6];
    const float* b2a = (const float*)d_in[7];
    const float* W2b = (const float*)d_in[8];
    const float* b2b = (const float*)d_in[9];
    float* out = (float*)d_out;

    const int* src = ei;
    const int* dst = ei + N_EDGES;

    // Workspace: bf16 xb[N,64] t1[N,64] h[N,128] t2[N,128] | bf16 weightsT |
    //            int deg/off/bsum/rank | ushort nbr[E]
    unsigned short* xb = (unsigned short*)d_ws;
    unsigned short* t1 = xb + (size_t)N_NODES * 64;
    unsigned short* h  = t1 + (size_t)N_NODES * 64;
    unsigned short* t2 = h + (size_t)N_NODES * 128;
    unsigned short* W1aT = t2 + (size_t)N_NODES * 128;
    unsigned short* W1bT = W1aT + 8192;
    unsigned short* W2aT = W1bT + 16384;
    unsigned short* W2bT = W2aT + 16384;
    int* deg  = (int*)(W2bT + 8192);
    int* off  = deg + N_NODES;
    int* bsum = off + N_NODES + 1;
    int* rank = bsum + 64;
    unsigned short* nbr = (unsigned short*)(rank + N_EDGES);

    constexpr int NB = (N_NODES + 1023) / 1024;  // 49 scan blocks
    constexpr int PREP_THREADS = 49152 + N_NODES * 16 + N_NODES;

    // ---- Prep (weights + x convert + deg zero) ----
    prep_kernel<<<(PREP_THREADS + 255) / 256, 256, 0, stream>>>(
        W1a, W1b, W2a, W2b, x, W1aT, W1bT, W2aT, W2bT, xb, deg);

    // ---- CSR build ----
    hist_rank_kernel<<<(N_EDGES + 255) / 256, 256, 0, stream>>>(dst, deg, rank,
                                                                N_EDGES);
    scanA_kernel<<<NB, 1024, 0, stream>>>(deg, bsum, N_NODES);
    scanC_kernel<<<NB, 1024, 0, stream>>>(deg, bsum, off, N_NODES);
    fill_kernel<<<(N_EDGES + 255) / 256, 256, 0, stream>>>(src, dst, rank, off,
                                                           nbr, N_EDGES);

    // ---- Layer 1 ----
    gather1_kernel<<<(N_NODES + 15) / 16, 256, 0, stream>>>(xb, off, nbr, t1,
                                                            N_NODES);
    mlp_mfma_kernel<64, 128, 128, true>
        <<<(N_NODES + 63) / 64, 256, 0, stream>>>(t1, W1aT, b1a, W1bT, b1b, h,
                                                  N_NODES);

    // ---- Layer 2 ----
    gather2_kernel<<<(N_NODES + 15) / 16, 256, 0, stream>>>(h, off, nbr, t2,
                                                            N_NODES);
    mlp_mfma_kernel<128, 128, 64, false>
        <<<(N_NODES + 63) / 64, 256, 0, stream>>>(t2, W2aT, b2a, W2bT, b2b, out,
                                                  N_NODES);
}